// Round 1
// baseline (493.505 us; speedup 1.0000x reference)
//
#include <hip/hip_runtime.h>
#include <hip/hip_cooperative_groups.h>
#include <math.h>

namespace cg = cooperative_groups;

// ---------------------------------------------------------------------------
// SplineCNN net, MI355X. All geometry compile-time (tiled meshgrid).
// R5->R6: the 7-dispatch chain was gap/round-trip-dominated (no kernel made
// rocprof top-5; fills at 43us did). Fuse the whole net into ONE cooperative
// persistent kernel: 512 blocks x 256 threads (>=2 blocks/CU guaranteed by
// __launch_bounds__(256,2), 8.3KB LDS), 4 grid.sync()s:
//   [s1p1 || prepM] -> gemm2(S=3) -> redpool2 -> gemm3(S=9) -> [pool3+fc]
// redpool3+fc_head fused (h3p round trip gone, fc1 split-K over 256 thr).
// Fallback 6-dispatch path if cooperative launch is rejected.
// ---------------------------------------------------------------------------

#define DEV __device__ __forceinline__

DEV float elu_f(float v) { return v > 0.f ? v : expm1f(v); }

DEV void corners(float p0, float p1,
                 int& k00, int& k01, int& k10, int& k11,
                 float& w00, float& w01, float& w10, float& w11) {
  float v0 = fminf(fmaxf(p0, 0.f), 1.f) * 4.f;
  float v1 = fminf(fmaxf(p1, 0.f), 1.f) * 4.f;
  int i0 = (int)v0; i0 = i0 > 4 ? 4 : i0;
  int j0 = (int)v1; j0 = j0 > 4 ? 4 : j0;
  float f0 = v0 - (float)i0;
  float f1 = v1 - (float)j0;
  int i1 = i0 + 1 > 4 ? 4 : i0 + 1;
  int j1 = j0 + 1 > 4 ? 4 : j0 + 1;
  k00 = i0 * 5 + j0; k01 = i0 * 5 + j1; k10 = i1 * 5 + j0; k11 = i1 * 5 + j1;
  w00 = (1.f - f0) * (1.f - f1); w01 = (1.f - f0) * f1;
  w10 = f0 * (1.f - f1);         w11 = f0 * f1;
}

DEV float cellpos(int c, int gw) {
  return (gw == 6) ? (c < 5 ? 2.f + 5.f * (float)c : 26.f)
                   : (c < 3 ? 2.f + 7.5f * (float)c : 24.f);
}

__constant__ int c_dys[8] = {-1, -1, -1, 0, 0, 1, 1, 1};
__constant__ int c_dxs[8] = {-1, 0, 1, -1, 1, -1, 0, 1};

// ---- shared memory reused across stages (max 8.25 KB) ---------------------
union SMem {
  struct { float At[16][64]; float Bt[16][64]; int nbL[9]; } g;   // gemm
  struct { float h3[16][64]; float Al[256]; float part[256];
           float h4[128]; float lg[10]; } f;                      // fc stage
};

// ---------------- stage bodies (shared by fused + fallback) ----------------

// L1 stencil (1->32) + ELU + pool 28x28->6x6. id in [0, 294912)
DEV void s1p1_body(int id, const float* __restrict__ xin,
                   const float* __restrict__ W1, const float* __restrict__ root1,
                   const float* __restrict__ b1, float* __restrict__ h1p) {
  int g = id & 31, cell = id >> 5;
  int b = cell / 36, r = cell % 36;
  int cy = r / 6, cx = r % 6;
  int y0 = cy * 5, y1 = y0 + 5 > 28 ? 28 : y0 + 5;
  int x0 = cx * 5, x1 = x0 + 5 > 28 ? 28 : x0 + 5;
  float Wreg[8];
#pragma unroll
  for (int d = 0; d < 8; d++) {
    int k = (2 * c_dxs[d] + 2) * 5 + (2 * c_dys[d] + 2);  // frac==0
    Wreg[d] = W1[k * 32 + g];
  }
  float rt = root1[g], bs = b1[g];
  const float* xb = xin + b * 784;
  float vmax = -3.4e38f;
  for (int y = y0; y < y1; y++) {
    for (int x = x0; x < x1; x++) {
      float acc = 0.f;
#pragma unroll
      for (int d = 0; d < 8; d++) {
        int sy = y - c_dys[d], sx = x - c_dxs[d];
        if (sy >= 0 && sy < 28 && sx >= 0 && sx < 28)
          acc += xb[sy * 28 + sx] * Wreg[d];
      }
      float cnt = (float)((1 + (y > 0) + (y < 27)) * (1 + (x > 0) + (x < 27)) - 1);
      float v = acc * (1.f / cnt) + xb[y * 28 + x] * rt + bs;
      vmax = fmaxf(vmax, elu_f(v));
    }
  }
  h1p[cell * 32 + g] = vmax;
}

// M[c][d][f][g] = invc(c) * sum_corners w * W[k][f][g]; d==8 -> root.
// idx in [0, 663552 + 589824)
DEV void prepM_body(int idx, const float* __restrict__ W2,
                    const float* __restrict__ root2, const float* __restrict__ W3,
                    const float* __restrict__ root3, float* __restrict__ M2,
                    float* __restrict__ M3) {
  const int L2N = 36 * 9 * 32 * 64;
  int gw, F, c, d, f, g;
  const float *W, *root;
  float inv2M;
  float* Mout;
  int oidx;
  if (idx < L2N) {
    c = idx / 18432; int rem = idx % 18432;
    d = rem / 2048; f = (rem >> 6) & 31; g = rem & 63;
    gw = 6; F = 32; W = W2; root = root2; inv2M = 0.1f; Mout = M2; oidx = idx;
  } else {
    int j = idx - L2N;
    c = j / 36864; int rem = j % 36864;
    d = rem / 4096; f = (rem >> 6) & 63; g = rem & 63;
    gw = 4; F = 64; W = W3; root = root3; inv2M = 1.f / 15.f; Mout = M3; oidx = j;
  }
  float val = 0.f;
  if (d == 8) {
    val = root[f * 64 + g];
  } else {
    int cy = c / gw, cx = c % gw;
    int sy = cy - c_dys[d], sx = cx - c_dxs[d];
    if (sy >= 0 && sy < gw && sx >= 0 && sx < gw) {
      int cnt = (1 + (cy > 0) + (cy < gw - 1)) * (1 + (cx > 0) + (cx < gw - 1)) - 1;
      float invc = 1.f / (float)cnt;
      float p0 = (cellpos(cx, gw) - cellpos(sx, gw)) * inv2M + 0.5f;
      float p1 = (cellpos(cy, gw) - cellpos(sy, gw)) * inv2M + 0.5f;
      int k00, k01, k10, k11; float w00, w01, w10, w11;
      corners(p0, p1, k00, k01, k10, k11, w00, w01, w10, w11);
      val = invc * (w00 * W[(k00 * F + f) * 64 + g] + w01 * W[(k01 * F + f) * 64 + g] +
                    w10 * W[(k10 * F + f) * 64 + g] + w11 * W[(k11 * F + f) * 64 + g]);
    }
  }
  Mout[oidx] = val;
}

// class-GEMM partials P[s][c][256][64]; vb = (s*NC + c)*4 + rowtile
template <int PER, int FSHIFT, int NC, int DPS, int GW>
DEV void gemm_body(int vb, int t, SMem* sm, const float* __restrict__ X,
                   const float* __restrict__ M, float* __restrict__ P) {
  int s = vb / (4 * NC);
  int rem = vb - s * 4 * NC;
  int c = rem >> 2;
  int b0 = (rem & 3) * 64;
  constexpr int F = 1 << FSHIFT, fmask = F - 1;
  if (t < 9) {
    int cy = c / GW, cx = c % GW;
    int nbv = c;
    if (t < 8) {
      int sy = cy - c_dys[t], sx = cx - c_dxs[t];
      nbv = (sy >= 0 && sy < GW && sx >= 0 && sx < GW) ? sy * GW + sx : c;  // clamp: M==0
    }
    sm->g.nbL[t] = nbv;
  }
  __syncthreads();

  int tx = t & 15, ty = t >> 4;
  int kqA = (t & 3) * 4, rA = t >> 2;     // A staging: 4 ks at kqA, row rA
  int bkB = t >> 4, bnB = (t & 15) * 4;   // B staging
  float acc[4][4];
#pragma unroll
  for (int i = 0; i < 4; i++)
#pragma unroll
    for (int j = 0; j < 4; j++) acc[i][j] = 0.f;

  constexpr int chunkK = DPS << FSHIFT;
  for (int k0 = 0; k0 < chunkK; k0 += 16) {
    int kA = k0 + kqA;
    int dA = s * DPS + (kA >> FSHIFT);
    int fA = kA & fmask;
    float4 xv = *(const float4*)&X[(((b0 + rA) * PER + sm->g.nbL[dA]) << FSHIFT) + fA];
    int kB = k0 + bkB;
    int dB = s * DPS + (kB >> FSHIFT);
    int fB = kB & fmask;
    float4 bv = *(const float4*)&M[(size_t)(((c * 9 + dB) << FSHIFT) + fB) * 64 + bnB];
    __syncthreads();
    sm->g.At[kqA + 0][rA] = xv.x; sm->g.At[kqA + 1][rA] = xv.y;
    sm->g.At[kqA + 2][rA] = xv.z; sm->g.At[kqA + 3][rA] = xv.w;
    *(float4*)&sm->g.Bt[bkB][bnB] = bv;
    __syncthreads();
#pragma unroll
    for (int kk = 0; kk < 16; kk++) {
      float4 a = *(const float4*)&sm->g.At[kk][ty * 4];
      float4 bb = *(const float4*)&sm->g.Bt[kk][tx * 4];
      acc[0][0] += a.x * bb.x; acc[0][1] += a.x * bb.y; acc[0][2] += a.x * bb.z; acc[0][3] += a.x * bb.w;
      acc[1][0] += a.y * bb.x; acc[1][1] += a.y * bb.y; acc[1][2] += a.y * bb.z; acc[1][3] += a.y * bb.w;
      acc[2][0] += a.z * bb.x; acc[2][1] += a.z * bb.y; acc[2][2] += a.z * bb.z; acc[2][3] += a.z * bb.w;
      acc[3][0] += a.w * bb.x; acc[3][1] += a.w * bb.y; acc[3][2] += a.w * bb.z; acc[3][3] += a.w * bb.w;
    }
  }
  float* Pq = P + ((size_t)(s * NC + c) * 256 + b0) * 64;
#pragma unroll
  for (int i = 0; i < 4; i++) {
    float4 v = {acc[i][0], acc[i][1], acc[i][2], acc[i][3]};
    *(float4*)&Pq[(size_t)(ty * 4 + i) * 64 + tx * 4] = v;
  }
}

// L2: sum 3 partials + bias + ELU + pool 6x6->4x4. id in [0, 262144)
DEV void redpool2_body(int id, const float* __restrict__ P,
                       const float* __restrict__ bias, float* __restrict__ h2p) {
  int g = id & 63, s2 = id >> 6;
  int b = s2 >> 4, r = s2 & 15;
  int oy = r >> 2, ox = r & 3;
  int ys = oy == 0 ? 0 : (oy == 1 ? 1 : (oy == 2 ? 3 : 4));
  int yn = (oy == 1 || oy == 3) ? 2 : 1;
  int xs = ox == 0 ? 0 : (ox == 1 ? 1 : (ox == 2 ? 3 : 4));
  int xn = (ox == 1 || ox == 3) ? 2 : 1;
  float bg = bias[g];
  const size_t CS = (size_t)36 * 256 * 64;
  float vmax = -3.4e38f;
  for (int yy = ys; yy < ys + yn; yy++)
    for (int xx = xs; xx < xs + xn; xx++) {
      size_t e = (size_t)((yy * 6 + xx) * 256 + b) * 64 + g;
      float v = P[e] + P[CS + e] + P[2 * CS + e] + bg;
      vmax = fmaxf(vmax, elu_f(v));
    }
  h2p[(size_t)s2 * 64 + g] = vmax;
}

// L3 reduce(9 partials)+bias+ELU + pool 4x4->2x2 + FC1+ELU + FC2 + logsoftmax
// one unit per image b, 256 threads.
DEV void fc_body(int b, int t, SMem* sm, const float* __restrict__ P,
                 const float* __restrict__ b3, const float* __restrict__ fc1w,
                 const float* __restrict__ fc1b, const float* __restrict__ fc2w,
                 const float* __restrict__ fc2b, float* __restrict__ out) {
  const size_t CS = (size_t)16 * 256 * 64;
  // sum partials + bias + ELU -> h3[16][64]
#pragma unroll
  for (int i = 0; i < 4; i++) {
    int idx = i * 256 + t;            // 0..1023
    int cell = idx >> 6, g = idx & 63;
    float v = b3[g];
    size_t e = (size_t)(cell * 256 + b) * 64 + g;
#pragma unroll
    for (int q = 0; q < 9; q++) v += P[q * CS + e];
    sm->f.h3[cell][g] = elu_f(v);
  }
  __syncthreads();
  // pool 4x4 -> 2x2 into Al[r*64+g], r = oy*2+ox
  {
    int r = t >> 6, g = t & 63;
    int oy = r >> 1, ox = r & 1;
    float m = -3.4e38f;
#pragma unroll
    for (int i = 0; i < 2; i++)
#pragma unroll
      for (int j = 0; j < 2; j++)
        m = fmaxf(m, sm->f.h3[(oy * 2 + i) * 4 + (ox * 2 + j)][g]);
    sm->f.Al[t] = m;
  }
  __syncthreads();
  // FC1 split-K: t = half*128 + o
  {
    int o = t & 127, half = t >> 7;
    float acc = 0.f;
    const float* wcol = fc1w + o;
#pragma unroll 8
    for (int k = half * 128; k < half * 128 + 128; k++)
      acc += sm->f.Al[k] * wcol[k * 128];
    sm->f.part[t] = acc;
  }
  __syncthreads();
  if (t < 128)
    sm->f.h4[t] = elu_f(sm->f.part[t] + sm->f.part[t + 128] + fc1b[t]);
  __syncthreads();
  if (t < 10) {
    float l = fc2b[t];
#pragma unroll 8
    for (int k = 0; k < 128; k++) l += sm->f.h4[k] * fc2w[k * 10 + t];
    sm->f.lg[t] = l;
  }
  __syncthreads();
  if (t < 10) {
    float m = sm->f.lg[0];
#pragma unroll
    for (int j = 1; j < 10; j++) m = fmaxf(m, sm->f.lg[j]);
    float ssum = 0.f;
#pragma unroll
    for (int j = 0; j < 10; j++) ssum += expf(sm->f.lg[j] - m);
    out[b * 10 + t] = sm->f.lg[t] - m - logf(ssum);
  }
}

// ---------------------------- fused cooperative kernel ---------------------
struct NetArgs {
  const float *x, *W1, *root1, *b1;
  const float *W2, *root2, *b2;
  const float *W3, *root3, *b3;
  const float *fc1w, *fc1b, *fc2w, *fc2b;
  float *out;
  float *h1p, *M2, *M3, *P, *h2p;
};

__global__ __launch_bounds__(256, 2) void net_kernel(NetArgs a) {
  __shared__ SMem sm;
  cg::grid_group grid = cg::this_grid();
  const int t = threadIdx.x;
  const int nblk = gridDim.x;

  // stage A: s1p1 (1152 units) || prepM (4896 units)
  for (int vb = blockIdx.x; vb < 6048; vb += nblk) {
    if (vb < 1152) s1p1_body(vb * 256 + t, a.x, a.W1, a.root1, a.b1, a.h1p);
    else           prepM_body((vb - 1152) * 256 + t, a.W2, a.root2, a.W3, a.root3,
                              a.M2, a.M3);
  }
  __threadfence();
  grid.sync();
  // stage B: L2 class-GEMM, 36 classes x 4 rowtiles x S=3 = 432 units
  for (int vb = blockIdx.x; vb < 432; vb += nblk)
    gemm_body<36, 5, 36, 3, 6>(vb, t, &sm, a.h1p, a.M2, a.P);
  __threadfence();
  grid.sync();
  // stage C: reduce+ELU+pool 6x6->4x4, 1024 units
  for (int vb = blockIdx.x; vb < 1024; vb += nblk)
    redpool2_body(vb * 256 + t, a.P, a.b2, a.h2p);
  __threadfence();
  grid.sync();
  // stage D: L3 class-GEMM, 16 classes x 4 rowtiles x S=9 = 576 units
  for (int vb = blockIdx.x; vb < 576; vb += nblk)
    gemm_body<16, 6, 16, 1, 4>(vb, t, &sm, a.h2p, a.M3, a.P);
  __threadfence();
  grid.sync();
  // stage E: pool3 + FC head, one unit per image
  for (int vb = blockIdx.x; vb < 256; vb += nblk)
    fc_body(vb, t, &sm, a.P, a.b3, a.fc1w, a.fc1b, a.fc2w, a.fc2b, a.out);
}

// ---------------------------- fallback wrappers ----------------------------
__global__ __launch_bounds__(256) void s1p1_kernel(
    const float* __restrict__ xin, const float* __restrict__ W1,
    const float* __restrict__ root1, const float* __restrict__ b1,
    float* __restrict__ h1p) {
  s1p1_body(blockIdx.x * 256 + threadIdx.x, xin, W1, root1, b1, h1p);
}

__global__ __launch_bounds__(256) void prepM_kernel(
    const float* __restrict__ W2, const float* __restrict__ root2,
    const float* __restrict__ W3, const float* __restrict__ root3,
    float* __restrict__ M2, float* __restrict__ M3) {
  prepM_body(blockIdx.x * 256 + threadIdx.x, W2, root2, W3, root3, M2, M3);
}

template <int PER, int FSHIFT, int NC, int DPS, int GW>
__global__ __launch_bounds__(256) void gemm_cls_tk(
    const float* __restrict__ X, const float* __restrict__ M,
    float* __restrict__ P) {
  __shared__ SMem sm;
  int vb = (blockIdx.z * NC + blockIdx.y) * 4 + blockIdx.x;
  gemm_body<PER, FSHIFT, NC, DPS, GW>(vb, threadIdx.x, &sm, X, M, P);
}

__global__ __launch_bounds__(256) void redpool2_kernel(
    const float* __restrict__ P, const float* __restrict__ bias,
    float* __restrict__ h2p) {
  redpool2_body(blockIdx.x * 256 + threadIdx.x, P, bias, h2p);
}

__global__ __launch_bounds__(256) void fc_fused_kernel(
    const float* __restrict__ P, const float* __restrict__ b3,
    const float* __restrict__ fc1w, const float* __restrict__ fc1b,
    const float* __restrict__ fc2w, const float* __restrict__ fc2b,
    float* __restrict__ out) {
  __shared__ SMem sm;
  fc_body(blockIdx.x, threadIdx.x, &sm, P, b3, fc1w, fc1b, fc2w, fc2b, out);
}

// ---------------------------------------------------------------------------
extern "C" void kernel_launch(void* const* d_in, const int* in_sizes, int n_in,
                              void* d_out, int out_size, void* d_ws, size_t ws_size,
                              hipStream_t stream) {
  const float* x     = (const float*)d_in[0];
  const float* W1    = (const float*)d_in[3];
  const float* root1 = (const float*)d_in[4];
  const float* b1    = (const float*)d_in[5];
  const float* W2    = (const float*)d_in[6];
  const float* root2 = (const float*)d_in[7];
  const float* b2    = (const float*)d_in[8];
  const float* W3    = (const float*)d_in[9];
  const float* root3 = (const float*)d_in[10];
  const float* b3    = (const float*)d_in[11];
  const float* fc1w  = (const float*)d_in[12];
  const float* fc1b  = (const float*)d_in[13];
  const float* fc2w  = (const float*)d_in[14];
  const float* fc2b  = (const float*)d_in[15];
  float* out = (float*)d_out;

  float* ws = (float*)d_ws;
  size_t o = 0;
  float* w_h1p = ws + o; o += (size_t)9216 * 32;          // 294912
  float* w_M2  = ws + o; o += (size_t)36 * 9 * 32 * 64;   // 663552
  float* w_M3  = ws + o; o += (size_t)16 * 9 * 64 * 64;   // 589824
  float* w_P   = ws + o; o += (size_t)9 * 16 * 256 * 64;  // 2359296 (>= L2's 3*36*256*64)
  float* w_h2p = ws + o; o += (size_t)4096 * 64;

  NetArgs a;
  a.x = x; a.W1 = W1; a.root1 = root1; a.b1 = b1;
  a.W2 = W2; a.root2 = root2; a.b2 = b2;
  a.W3 = W3; a.root3 = root3; a.b3 = b3;
  a.fc1w = fc1w; a.fc1b = fc1b; a.fc2w = fc2w; a.fc2b = fc2b;
  a.out = out;
  a.h1p = w_h1p; a.M2 = w_M2; a.M3 = w_M3; a.P = w_P; a.h2p = w_h2p;

  // grid: min(512, actual co-resident capacity). __launch_bounds__(256,2)
  // guarantees >=2 blocks/CU (VGPR capped at 256, LDS 8.25KB), so 512 fits.
  static int s_grid = 0;
  if (s_grid == 0) {
    int perCU = 0;
    if (hipOccupancyMaxActiveBlocksPerMultiprocessor(
            &perCU, (const void*)net_kernel, 256, 0) != hipSuccess || perCU <= 0)
      perCU = 2;
    long g = (long)perCU * 256;
    s_grid = (int)(g < 512 ? g : 512);
  }

  void* kargs[] = { (void*)&a };
  hipError_t err = hipLaunchCooperativeKernel((const void*)net_kernel,
                                              dim3(s_grid), dim3(256), kargs,
                                              0, stream);
  if (err != hipSuccess) {
    (void)hipGetLastError();  // clear; fall back to 6-dispatch path
    s1p1_kernel<<<1152, 256, 0, stream>>>(x, W1, root1, b1, w_h1p);
    prepM_kernel<<<4896, 256, 0, stream>>>(W2, root2, W3, root3, w_M2, w_M3);
    gemm_cls_tk<36, 5, 36, 3, 6><<<dim3(4, 36, 3), 256, 0, stream>>>(w_h1p, w_M2, w_P);
    redpool2_kernel<<<1024, 256, 0, stream>>>(w_P, b2, w_h2p);
    gemm_cls_tk<16, 6, 16, 1, 4><<<dim3(4, 16, 9), 256, 0, stream>>>(w_h2p, w_M3, w_P);
    fc_fused_kernel<<<256, 256, 0, stream>>>(w_P, b3, fc1w, fc1b, fc2w, fc2b, out);
  }
}

// Round 2
// 205.699 us; speedup vs baseline: 2.3992x; 2.3992x over previous
//
#include <hip/hip_runtime.h>
#include <math.h>

// ---------------------------------------------------------------------------
// SplineCNN net, MI355X. All geometry compile-time (tiled meshgrid).
// R6->R7: cooperative grid.sync measured ~100+us/sync on gfx950 (net_kernel
// 560us, VALUBusy 5%) -> revert to dispatches. New lever: ELU is monotone and
// bias is per-channel, so pool_max(elu(sum+bias)) = elu(max(sum)+bias).
// Class-GEMMs therefore run FULL-K (no S-split, no P partials) and fold
// pooling into deterministic atomicMax (monotone float->uint map).
// 4 dispatches:
//   prep[s1p1 || prepM || zero(h2raw,h3raw)]
//   -> gemm2 (K=288, 36c x 4 rowtiles=144 blk, atomicMax -> h2raw)
//   -> gemm3 (K=576, 16c x 8 rowtiles=128 blk, A-load does elu(max+b2),
//             atomicMax -> h3raw)
//   -> fc    (Al = elu(unmap(h3raw)+b3), FC1 split-K, FC2, log_softmax)
// Kills P round-trips (~30MB), redpool2/redpool3 kernels, h3p round trip,
// and 3 dispatch boundaries.
// ---------------------------------------------------------------------------

#define DEV __device__ __forceinline__

DEV float elu_f(float v) { return v > 0.f ? v : expm1f(v); }

// order-preserving float<->uint map for atomicMax; 0u acts as -inf sentinel
DEV unsigned int fmap(float f) {
  unsigned int b = __float_as_uint(f);
  return (b & 0x80000000u) ? ~b : (b | 0x80000000u);
}
DEV float funmap(unsigned int u) {
  unsigned int b = (u & 0x80000000u) ? (u & 0x7fffffffu) : ~u;
  return __uint_as_float(b);
}

DEV void corners(float p0, float p1,
                 int& k00, int& k01, int& k10, int& k11,
                 float& w00, float& w01, float& w10, float& w11) {
  float v0 = fminf(fmaxf(p0, 0.f), 1.f) * 4.f;
  float v1 = fminf(fmaxf(p1, 0.f), 1.f) * 4.f;
  int i0 = (int)v0; i0 = i0 > 4 ? 4 : i0;
  int j0 = (int)v1; j0 = j0 > 4 ? 4 : j0;
  float f0 = v0 - (float)i0;
  float f1 = v1 - (float)j0;
  int i1 = i0 + 1 > 4 ? 4 : i0 + 1;
  int j1 = j0 + 1 > 4 ? 4 : j0 + 1;
  k00 = i0 * 5 + j0; k01 = i0 * 5 + j1; k10 = i1 * 5 + j0; k11 = i1 * 5 + j1;
  w00 = (1.f - f0) * (1.f - f1); w01 = (1.f - f0) * f1;
  w10 = f0 * (1.f - f1);         w11 = f0 * f1;
}

DEV float cellpos(int c, int gw) {
  return (gw == 6) ? (c < 5 ? 2.f + 5.f * (float)c : 26.f)
                   : (c < 3 ? 2.f + 7.5f * (float)c : 24.f);
}

// 6x6 -> 4x4 pool class map {0,1,1,2,3,3}
DEV int ymap6(int c) { return c == 0 ? 0 : (c <= 2 ? 1 : (c == 3 ? 2 : 3)); }

__constant__ int c_dys[8] = {-1, -1, -1, 0, 0, 1, 1, 1};
__constant__ int c_dxs[8] = {-1, 0, 1, -1, 1, -1, 0, 1};

// ---------------- stage bodies --------------------------------------------

// L1 stencil (1->32) + ELU + pool 28x28->6x6. id in [0, 294912)
DEV void s1p1_body(int id, const float* __restrict__ xin,
                   const float* __restrict__ W1, const float* __restrict__ root1,
                   const float* __restrict__ b1, float* __restrict__ h1p) {
  int g = id & 31, cell = id >> 5;
  int b = cell / 36, r = cell % 36;
  int cy = r / 6, cx = r % 6;
  int y0 = cy * 5, y1 = y0 + 5 > 28 ? 28 : y0 + 5;
  int x0 = cx * 5, x1 = x0 + 5 > 28 ? 28 : x0 + 5;
  float Wreg[8];
#pragma unroll
  for (int d = 0; d < 8; d++) {
    int k = (2 * c_dxs[d] + 2) * 5 + (2 * c_dys[d] + 2);  // frac==0
    Wreg[d] = W1[k * 32 + g];
  }
  float rt = root1[g], bs = b1[g];
  const float* xb = xin + b * 784;
  float vmax = -3.4e38f;
  for (int y = y0; y < y1; y++) {
    for (int x = x0; x < x1; x++) {
      float acc = 0.f;
#pragma unroll
      for (int d = 0; d < 8; d++) {
        int sy = y - c_dys[d], sx = x - c_dxs[d];
        if (sy >= 0 && sy < 28 && sx >= 0 && sx < 28)
          acc += xb[sy * 28 + sx] * Wreg[d];
      }
      float cnt = (float)((1 + (y > 0) + (y < 27)) * (1 + (x > 0) + (x < 27)) - 1);
      float v = acc * (1.f / cnt) + xb[y * 28 + x] * rt + bs;
      vmax = fmaxf(vmax, elu_f(v));
    }
  }
  h1p[cell * 32 + g] = vmax;
}

// M[c][d][f][g] = invc(c) * sum_corners w * W[k][f][g]; d==8 -> root.
DEV void prepM_body(int idx, const float* __restrict__ W2,
                    const float* __restrict__ root2, const float* __restrict__ W3,
                    const float* __restrict__ root3, float* __restrict__ M2,
                    float* __restrict__ M3) {
  const int L2N = 36 * 9 * 32 * 64;
  int gw, F, c, d, f, g;
  const float *W, *root;
  float inv2M;
  float* Mout;
  int oidx;
  if (idx < L2N) {
    c = idx / 18432; int rem = idx % 18432;
    d = rem / 2048; f = (rem >> 6) & 31; g = rem & 63;
    gw = 6; F = 32; W = W2; root = root2; inv2M = 0.1f; Mout = M2; oidx = idx;
  } else {
    int j = idx - L2N;
    c = j / 36864; int rem = j % 36864;
    d = rem / 4096; f = (rem >> 6) & 63; g = rem & 63;
    gw = 4; F = 64; W = W3; root = root3; inv2M = 1.f / 15.f; Mout = M3; oidx = j;
  }
  float val = 0.f;
  if (d == 8) {
    val = root[f * 64 + g];
  } else {
    int cy = c / gw, cx = c % gw;
    int sy = cy - c_dys[d], sx = cx - c_dxs[d];
    if (sy >= 0 && sy < gw && sx >= 0 && sx < gw) {
      int cnt = (1 + (cy > 0) + (cy < gw - 1)) * (1 + (cx > 0) + (cx < gw - 1)) - 1;
      float invc = 1.f / (float)cnt;
      float p0 = (cellpos(cx, gw) - cellpos(sx, gw)) * inv2M + 0.5f;
      float p1 = (cellpos(cy, gw) - cellpos(sy, gw)) * inv2M + 0.5f;
      int k00, k01, k10, k11; float w00, w01, w10, w11;
      corners(p0, p1, k00, k01, k10, k11, w00, w01, w10, w11);
      val = invc * (w00 * W[(k00 * F + f) * 64 + g] + w01 * W[(k01 * F + f) * 64 + g] +
                    w10 * W[(k10 * F + f) * 64 + g] + w11 * W[(k11 * F + f) * 64 + g]);
    }
  }
  Mout[oidx] = val;
}

// ---------------- D1: s1p1 || prepM || zero raw buffers --------------------
__global__ __launch_bounds__(256) void prep_kernel(
    const float* __restrict__ x, const float* __restrict__ W1,
    const float* __restrict__ root1, const float* __restrict__ b1,
    const float* __restrict__ W2, const float* __restrict__ root2,
    const float* __restrict__ W3, const float* __restrict__ root3,
    float* __restrict__ h1p, float* __restrict__ M2, float* __restrict__ M3,
    unsigned int* __restrict__ h2raw, unsigned int* __restrict__ h3raw) {
  int vb = blockIdx.x, t = threadIdx.x;
  if (vb < 1152) {
    s1p1_body(vb * 256 + t, x, W1, root1, b1, h1p);
  } else if (vb < 6048) {
    prepM_body((vb - 1152) * 256 + t, W2, root2, W3, root3, M2, M3);
  } else {
    int id = (vb - 6048) * 256 + t;  // 0 .. 327679
    if (id < 262144) h2raw[id] = 0u;
    else             h3raw[id - 262144] = 0u;
  }
}

// ---------------- D2: L2 class-GEMM full-K=288, atomicMax pool -------------
// grid = 36 classes * 4 rowtiles(64) = 144 blocks, 256 threads, acc 4x4
__global__ __launch_bounds__(256) void gemm2_kernel(
    const float* __restrict__ X, const float* __restrict__ M2,
    unsigned int* __restrict__ h2raw) {
  __shared__ float At[16][64];
  __shared__ float Bt[16][64];
  __shared__ int nbL[9];
  int t = threadIdx.x;
  int c = blockIdx.x >> 2;
  int b0 = (blockIdx.x & 3) * 64;
  int cy = c / 6, cx = c % 6;
  if (t < 9) {
    int nbv = c;
    if (t < 8) {
      int sy = cy - c_dys[t], sx = cx - c_dxs[t];
      nbv = (sy >= 0 && sy < 6 && sx >= 0 && sx < 6) ? sy * 6 + sx : c;  // M==0
    }
    nbL[t] = nbv;
  }
  __syncthreads();

  int tx = t & 15, ty = t >> 4;
  int kqA = (t & 3) * 4, rA = t >> 2;
  int bkB = t >> 4, bnB = (t & 15) * 4;
  float acc[4][4];
#pragma unroll
  for (int i = 0; i < 4; i++)
#pragma unroll
    for (int j = 0; j < 4; j++) acc[i][j] = 0.f;

  for (int k0 = 0; k0 < 288; k0 += 16) {
    int d = k0 >> 5, fb = k0 & 31;
    float4 xv = *(const float4*)&X[(((b0 + rA) * 36 + nbL[d]) << 5) + fb + kqA];
    float4 bv = *(const float4*)&M2[(size_t)(((c * 9 + d) << 5) + fb + bkB) * 64 + bnB];
    __syncthreads();
    At[kqA + 0][rA] = xv.x; At[kqA + 1][rA] = xv.y;
    At[kqA + 2][rA] = xv.z; At[kqA + 3][rA] = xv.w;
    *(float4*)&Bt[bkB][bnB] = bv;
    __syncthreads();
#pragma unroll
    for (int kk = 0; kk < 16; kk++) {
      float4 a = *(const float4*)&At[kk][ty * 4];
      float4 bb = *(const float4*)&Bt[kk][tx * 4];
      acc[0][0] += a.x * bb.x; acc[0][1] += a.x * bb.y; acc[0][2] += a.x * bb.z; acc[0][3] += a.x * bb.w;
      acc[1][0] += a.y * bb.x; acc[1][1] += a.y * bb.y; acc[1][2] += a.y * bb.z; acc[1][3] += a.y * bb.w;
      acc[2][0] += a.z * bb.x; acc[2][1] += a.z * bb.y; acc[2][2] += a.z * bb.z; acc[2][3] += a.z * bb.w;
      acc[3][0] += a.w * bb.x; acc[3][1] += a.w * bb.y; acc[3][2] += a.w * bb.z; acc[3][3] += a.w * bb.w;
    }
  }
  int r = ymap6(cy) * 4 + ymap6(cx);
#pragma unroll
  for (int i = 0; i < 4; i++) {
    int b = b0 + ty * 4 + i;
    unsigned int* dst = &h2raw[(size_t)(b * 16 + r) * 64 + tx * 4];
#pragma unroll
    for (int j = 0; j < 4; j++) atomicMax(&dst[j], fmap(acc[i][j]));
  }
}

// ---------------- D3: L3 class-GEMM full-K=576, atomicMax pool -------------
// grid = 16 classes * 8 rowtiles(32) = 128 blocks, 256 threads, acc 2x4.
// A-load materializes h2p on the fly: elu(unmap(h2raw)+b2).
__global__ __launch_bounds__(256) void gemm3_kernel(
    const unsigned int* __restrict__ H2, const float* __restrict__ M3,
    const float* __restrict__ b2, unsigned int* __restrict__ h3raw) {
  __shared__ float At[16][32];
  __shared__ float Bt[16][64];
  __shared__ int nbL[9];
  int t = threadIdx.x;
  int c = blockIdx.x >> 3;
  int b0 = (blockIdx.x & 7) * 32;
  int cy = c >> 2, cx = c & 3;
  if (t < 9) {
    int nbv = c;
    if (t < 8) {
      int sy = cy - c_dys[t], sx = cx - c_dxs[t];
      nbv = (sy >= 0 && sy < 4 && sx >= 0 && sx < 4) ? sy * 4 + sx : c;  // M==0
    }
    nbL[t] = nbv;
  }
  __syncthreads();

  int tx = t & 15, ty = t >> 4;
  int rr = t >> 3, fo = (t & 7) * 2;   // A staging: row rr, 2 f at fo
  int bkB = t >> 4, bnB = (t & 15) * 4;
  float acc[2][4];
#pragma unroll
  for (int i = 0; i < 2; i++)
#pragma unroll
    for (int j = 0; j < 4; j++) acc[i][j] = 0.f;

  for (int k0 = 0; k0 < 576; k0 += 16) {
    int d = k0 >> 6, fb = (k0 & 63);
    int f = fb + fo;
    uint2 hv = *(const uint2*)&H2[(size_t)(((b0 + rr) * 16 + nbL[d]) << 6) + f];
    float a0 = elu_f(funmap(hv.x) + b2[f]);
    float a1 = elu_f(funmap(hv.y) + b2[f + 1]);
    float4 bv = *(const float4*)&M3[(size_t)(((c * 9 + d) << 6) + fb + bkB) * 64 + bnB];
    __syncthreads();
    At[fo + 0][rr] = a0; At[fo + 1][rr] = a1;
    *(float4*)&Bt[bkB][bnB] = bv;
    __syncthreads();
#pragma unroll
    for (int kk = 0; kk < 16; kk++) {
      float a0c = At[kk][ty * 2 + 0];
      float a1c = At[kk][ty * 2 + 1];
      float4 bb = *(const float4*)&Bt[kk][tx * 4];
      acc[0][0] += a0c * bb.x; acc[0][1] += a0c * bb.y; acc[0][2] += a0c * bb.z; acc[0][3] += a0c * bb.w;
      acc[1][0] += a1c * bb.x; acc[1][1] += a1c * bb.y; acc[1][2] += a1c * bb.z; acc[1][3] += a1c * bb.w;
    }
  }
  int r = (cy >> 1) * 2 + (cx >> 1);  // 4x4 -> 2x2 pool map {0,0,1,1}
#pragma unroll
  for (int i = 0; i < 2; i++) {
    int b = b0 + ty * 2 + i;
    unsigned int* dst = &h3raw[(size_t)(b * 4 + r) * 64 + tx * 4];
#pragma unroll
    for (int j = 0; j < 4; j++) atomicMax(&dst[j], fmap(acc[i][j]));
  }
}

// ---------------- D4: FC head ----------------------------------------------
// Al = elu(unmap(h3raw)+b3); FC1 split-K over 256 thr; FC2; log_softmax.
__global__ __launch_bounds__(256) void fc_kernel(
    const unsigned int* __restrict__ h3raw, const float* __restrict__ b3,
    const float* __restrict__ fc1w, const float* __restrict__ fc1b,
    const float* __restrict__ fc2w, const float* __restrict__ fc2b,
    float* __restrict__ out) {
  __shared__ float Al[256];
  __shared__ float part[256];
  __shared__ float h4[128];
  __shared__ float lg[10];
  int b = blockIdx.x, t = threadIdx.x;
  Al[t] = elu_f(funmap(h3raw[b * 256 + t]) + b3[t & 63]);
  __syncthreads();
  {
    int o = t & 127, half = t >> 7;
    float acc = 0.f;
    const float* wcol = fc1w + o;
#pragma unroll 8
    for (int k = half * 128; k < half * 128 + 128; k++)
      acc += Al[k] * wcol[k * 128];
    part[t] = acc;
  }
  __syncthreads();
  if (t < 128)
    h4[t] = elu_f(part[t] + part[t + 128] + fc1b[t]);
  __syncthreads();
  if (t < 10) {
    float l = fc2b[t];
#pragma unroll 8
    for (int k = 0; k < 128; k++) l += h4[k] * fc2w[k * 10 + t];
    lg[t] = l;
  }
  __syncthreads();
  if (t < 10) {
    float m = lg[0];
#pragma unroll
    for (int j = 1; j < 10; j++) m = fmaxf(m, lg[j]);
    float ssum = 0.f;
#pragma unroll
    for (int j = 0; j < 10; j++) ssum += expf(lg[j] - m);
    out[b * 10 + t] = lg[t] - m - logf(ssum);
  }
}

// ---------------------------------------------------------------------------
extern "C" void kernel_launch(void* const* d_in, const int* in_sizes, int n_in,
                              void* d_out, int out_size, void* d_ws, size_t ws_size,
                              hipStream_t stream) {
  const float* x     = (const float*)d_in[0];
  const float* W1    = (const float*)d_in[3];
  const float* root1 = (const float*)d_in[4];
  const float* b1    = (const float*)d_in[5];
  const float* W2    = (const float*)d_in[6];
  const float* root2 = (const float*)d_in[7];
  const float* b2    = (const float*)d_in[8];
  const float* W3    = (const float*)d_in[9];
  const float* root3 = (const float*)d_in[10];
  const float* b3    = (const float*)d_in[11];
  const float* fc1w  = (const float*)d_in[12];
  const float* fc1b  = (const float*)d_in[13];
  const float* fc2w  = (const float*)d_in[14];
  const float* fc2b  = (const float*)d_in[15];
  float* out = (float*)d_out;

  float* ws = (float*)d_ws;
  size_t o = 0;
  float* w_h1p = ws + o; o += (size_t)9216 * 32;          // 294912
  float* w_M2  = ws + o; o += (size_t)36 * 9 * 32 * 64;   // 663552
  float* w_M3  = ws + o; o += (size_t)16 * 9 * 64 * 64;   // 589824
  unsigned int* w_h2raw = (unsigned int*)(ws + o); o += 262144;  // 256*16*64
  unsigned int* w_h3raw = (unsigned int*)(ws + o); o += 65536;   // 256*4*64

  // D1: s1p1 (1152) || prepM (4896) || zero h2raw+h3raw (1280)
  prep_kernel<<<7328, 256, 0, stream>>>(x, W1, root1, b1, W2, root2, W3, root3,
                                        w_h1p, w_M2, w_M3, w_h2raw, w_h3raw);
  // D2: L2 full-K class-GEMM + fused max-pool (6x6 -> 4x4)
  gemm2_kernel<<<144, 256, 0, stream>>>(w_h1p, w_M2, w_h2raw);
  // D3: L3 full-K class-GEMM (elu+bias on A-load) + fused max-pool (4x4->2x2)
  gemm3_kernel<<<128, 256, 0, stream>>>(w_h2raw, w_M3, b2, w_h3raw);
  // D4: FC head
  fc_kernel<<<256, 256, 0, stream>>>(w_h3raw, b3, fc1w, fc1b, fc2w, fc2b, out);
}

// Round 3
// 162.120 us; speedup vs baseline: 3.0441x; 1.2688x over previous
//
#include <hip/hip_runtime.h>
#include <math.h>

// ---------------------------------------------------------------------------
// SplineCNN net, MI355X. All geometry compile-time (tiled meshgrid).
// R7 post-mortem: atomic full-K GEMMs (144/128 blocks) underfilled the 256-CU
// chip and paid cross-XCD atomic latency -> slower than split-K. Revert to
// the verified R5 split-K skeleton; keep only safe structural merges:
//   D1 prep   = s1p1 (interior fast path) || prepM           [-1 boundary]
//   D2 gemm2  = S=3 split-K class-GEMM, 432 blocks -> P      [as R5]
//   D3 redpool2 = sum3+bias+ELU+pool 6x6->4x4 -> h2p         [as R5]
//   D4 gemm3  = S=9 split-K class-GEMM, 576 blocks -> P      [as R5]
//   D5 fc_fused = redpool3 + FC head (verified in R6 coop)   [-1 boundary,
//                                                             -h3p roundtrip]
// ---------------------------------------------------------------------------

#define DEV __device__ __forceinline__

DEV float elu_f(float v) { return v > 0.f ? v : expm1f(v); }

DEV void corners(float p0, float p1,
                 int& k00, int& k01, int& k10, int& k11,
                 float& w00, float& w01, float& w10, float& w11) {
  float v0 = fminf(fmaxf(p0, 0.f), 1.f) * 4.f;
  float v1 = fminf(fmaxf(p1, 0.f), 1.f) * 4.f;
  int i0 = (int)v0; i0 = i0 > 4 ? 4 : i0;
  int j0 = (int)v1; j0 = j0 > 4 ? 4 : j0;
  float f0 = v0 - (float)i0;
  float f1 = v1 - (float)j0;
  int i1 = i0 + 1 > 4 ? 4 : i0 + 1;
  int j1 = j0 + 1 > 4 ? 4 : j0 + 1;
  k00 = i0 * 5 + j0; k01 = i0 * 5 + j1; k10 = i1 * 5 + j0; k11 = i1 * 5 + j1;
  w00 = (1.f - f0) * (1.f - f1); w01 = (1.f - f0) * f1;
  w10 = f0 * (1.f - f1);         w11 = f0 * f1;
}

DEV float cellpos(int c, int gw) {
  return (gw == 6) ? (c < 5 ? 2.f + 5.f * (float)c : 26.f)
                   : (c < 3 ? 2.f + 7.5f * (float)c : 24.f);
}

__constant__ int c_dys[8] = {-1, -1, -1, 0, 0, 1, 1, 1};
__constant__ int c_dxs[8] = {-1, 0, 1, -1, 1, -1, 0, 1};

// ---------------- stage bodies --------------------------------------------

// L1 stencil (1->32) + ELU + pool 28x28->6x6. id in [0, 294912)
// Per-pixel interior fast path: ~90% of pixels need no bounds checks, cnt=8.
DEV void s1p1_body(int id, const float* __restrict__ xin,
                   const float* __restrict__ W1, const float* __restrict__ root1,
                   const float* __restrict__ b1, float* __restrict__ h1p) {
  int g = id & 31, cell = id >> 5;
  int b = cell / 36, r = cell % 36;
  int cy = r / 6, cx = r % 6;
  int y0 = cy * 5, y1 = y0 + 5 > 28 ? 28 : y0 + 5;
  int x0 = cx * 5, x1 = x0 + 5 > 28 ? 28 : x0 + 5;
  float Wreg[8];
#pragma unroll
  for (int d = 0; d < 8; d++) {
    int k = (2 * c_dxs[d] + 2) * 5 + (2 * c_dys[d] + 2);  // frac==0
    Wreg[d] = W1[k * 32 + g];
  }
  float rt = root1[g], bs = b1[g];
  const float* xb = xin + b * 784;
  float vmax = -3.4e38f;
  for (int y = y0; y < y1; y++) {
    bool yin = (y > 0) && (y < 27);
    for (int x = x0; x < x1; x++) {
      float v;
      if (yin && (x > 0) && (x < 27)) {
        float acc = 0.f;
#pragma unroll
        for (int d = 0; d < 8; d++)
          acc += xb[(y - c_dys[d]) * 28 + (x - c_dxs[d])] * Wreg[d];
        v = acc * 0.125f + xb[y * 28 + x] * rt + bs;
      } else {
        float acc = 0.f;
#pragma unroll
        for (int d = 0; d < 8; d++) {
          int sy = y - c_dys[d], sx = x - c_dxs[d];
          if (sy >= 0 && sy < 28 && sx >= 0 && sx < 28)
            acc += xb[sy * 28 + sx] * Wreg[d];
        }
        float cnt = (float)((1 + (y > 0) + (y < 27)) * (1 + (x > 0) + (x < 27)) - 1);
        v = acc * (1.f / cnt) + xb[y * 28 + x] * rt + bs;
      }
      vmax = fmaxf(vmax, elu_f(v));
    }
  }
  h1p[cell * 32 + g] = vmax;
}

// M[c][d][f][g] = invc(c) * sum_corners w * W[k][f][g]; d==8 -> root.
DEV void prepM_body(int idx, const float* __restrict__ W2,
                    const float* __restrict__ root2, const float* __restrict__ W3,
                    const float* __restrict__ root3, float* __restrict__ M2,
                    float* __restrict__ M3) {
  const int L2N = 36 * 9 * 32 * 64;
  int gw, F, c, d, f, g;
  const float *W, *root;
  float inv2M;
  float* Mout;
  int oidx;
  if (idx < L2N) {
    c = idx / 18432; int rem = idx % 18432;
    d = rem / 2048; f = (rem >> 6) & 31; g = rem & 63;
    gw = 6; F = 32; W = W2; root = root2; inv2M = 0.1f; Mout = M2; oidx = idx;
  } else {
    int j = idx - L2N;
    c = j / 36864; int rem = j % 36864;
    d = rem / 4096; f = (rem >> 6) & 63; g = rem & 63;
    gw = 4; F = 64; W = W3; root = root3; inv2M = 1.f / 15.f; Mout = M3; oidx = j;
  }
  float val = 0.f;
  if (d == 8) {
    val = root[f * 64 + g];
  } else {
    int cy = c / gw, cx = c % gw;
    int sy = cy - c_dys[d], sx = cx - c_dxs[d];
    if (sy >= 0 && sy < gw && sx >= 0 && sx < gw) {
      int cnt = (1 + (cy > 0) + (cy < gw - 1)) * (1 + (cx > 0) + (cx < gw - 1)) - 1;
      float invc = 1.f / (float)cnt;
      float p0 = (cellpos(cx, gw) - cellpos(sx, gw)) * inv2M + 0.5f;
      float p1 = (cellpos(cy, gw) - cellpos(sy, gw)) * inv2M + 0.5f;
      int k00, k01, k10, k11; float w00, w01, w10, w11;
      corners(p0, p1, k00, k01, k10, k11, w00, w01, w10, w11);
      val = invc * (w00 * W[(k00 * F + f) * 64 + g] + w01 * W[(k01 * F + f) * 64 + g] +
                    w10 * W[(k10 * F + f) * 64 + g] + w11 * W[(k11 * F + f) * 64 + g]);
    }
  }
  Mout[oidx] = val;
}

// ---------------- D1: s1p1 || prepM ----------------------------------------
__global__ __launch_bounds__(256) void prep_kernel(
    const float* __restrict__ x, const float* __restrict__ W1,
    const float* __restrict__ root1, const float* __restrict__ b1,
    const float* __restrict__ W2, const float* __restrict__ root2,
    const float* __restrict__ W3, const float* __restrict__ root3,
    float* __restrict__ h1p, float* __restrict__ M2, float* __restrict__ M3) {
  int vb = blockIdx.x, t = threadIdx.x;
  if (vb < 1152) s1p1_body(vb * 256 + t, x, W1, root1, b1, h1p);
  else           prepM_body((vb - 1152) * 256 + t, W2, root2, W3, root3, M2, M3);
}

// ------------------ class-GEMM: P[s][c][256][64] partials ------------------
// vb = (s*NC + c)*4 + rowtile; 256 threads, 64x64 tile, 4x4 acc.
template <int PER, int FSHIFT, int NC, int DPS, int GW>
DEV void gemm_body(int vb, int t, const float* __restrict__ X,
                   const float* __restrict__ M, float* __restrict__ P) {
  __shared__ float At[16][64];
  __shared__ float Bt[16][64];
  __shared__ int nbL[9];
  int s = vb / (4 * NC);
  int rem = vb - s * 4 * NC;
  int c = rem >> 2;
  int b0 = (rem & 3) * 64;
  constexpr int F = 1 << FSHIFT, fmask = F - 1;
  if (t < 9) {
    int cy = c / GW, cx = c % GW;
    int nbv = c;
    if (t < 8) {
      int sy = cy - c_dys[t], sx = cx - c_dxs[t];
      nbv = (sy >= 0 && sy < GW && sx >= 0 && sx < GW) ? sy * GW + sx : c;  // M==0
    }
    nbL[t] = nbv;
  }
  __syncthreads();

  int tx = t & 15, ty = t >> 4;
  int kqA = (t & 3) * 4, rA = t >> 2;     // A staging: 4 ks at kqA, row rA
  int bkB = t >> 4, bnB = (t & 15) * 4;   // B staging
  float acc[4][4];
#pragma unroll
  for (int i = 0; i < 4; i++)
#pragma unroll
    for (int j = 0; j < 4; j++) acc[i][j] = 0.f;

  constexpr int chunkK = DPS << FSHIFT;
  for (int k0 = 0; k0 < chunkK; k0 += 16) {
    int kA = k0 + kqA;
    int dA = s * DPS + (kA >> FSHIFT);
    int fA = kA & fmask;
    float4 xv = *(const float4*)&X[(((b0 + rA) * PER + nbL[dA]) << FSHIFT) + fA];
    int kB = k0 + bkB;
    int dB = s * DPS + (kB >> FSHIFT);
    int fB = kB & fmask;
    float4 bv = *(const float4*)&M[(size_t)(((c * 9 + dB) << FSHIFT) + fB) * 64 + bnB];
    __syncthreads();
    At[kqA + 0][rA] = xv.x; At[kqA + 1][rA] = xv.y;
    At[kqA + 2][rA] = xv.z; At[kqA + 3][rA] = xv.w;
    *(float4*)&Bt[bkB][bnB] = bv;
    __syncthreads();
#pragma unroll
    for (int kk = 0; kk < 16; kk++) {
      float4 a = *(const float4*)&At[kk][ty * 4];
      float4 bb = *(const float4*)&Bt[kk][tx * 4];
      acc[0][0] += a.x * bb.x; acc[0][1] += a.x * bb.y; acc[0][2] += a.x * bb.z; acc[0][3] += a.x * bb.w;
      acc[1][0] += a.y * bb.x; acc[1][1] += a.y * bb.y; acc[1][2] += a.y * bb.z; acc[1][3] += a.y * bb.w;
      acc[2][0] += a.z * bb.x; acc[2][1] += a.z * bb.y; acc[2][2] += a.z * bb.z; acc[2][3] += a.z * bb.w;
      acc[3][0] += a.w * bb.x; acc[3][1] += a.w * bb.y; acc[3][2] += a.w * bb.z; acc[3][3] += a.w * bb.w;
    }
  }
  float* Pq = P + ((size_t)(s * NC + c) * 256 + b0) * 64;
#pragma unroll
  for (int i = 0; i < 4; i++) {
    float4 v = {acc[i][0], acc[i][1], acc[i][2], acc[i][3]};
    *(float4*)&Pq[(size_t)(ty * 4 + i) * 64 + tx * 4] = v;
  }
}

template <int PER, int FSHIFT, int NC, int DPS, int GW>
__global__ __launch_bounds__(256) void gemm_cls_tk(
    const float* __restrict__ X, const float* __restrict__ M,
    float* __restrict__ P) {
  int vb = (blockIdx.z * NC + blockIdx.y) * 4 + blockIdx.x;
  gemm_body<PER, FSHIFT, NC, DPS, GW>(vb, threadIdx.x, X, M, P);
}

// ---- D3: sum 3 partials + bias + ELU + pool 6x6->4x4 -> h2p[b*16+cell] ----
__global__ __launch_bounds__(256) void redpool2_kernel(
    const float* __restrict__ P, const float* __restrict__ bias,
    float* __restrict__ h2p) {
  int id = blockIdx.x * 256 + threadIdx.x;  // 256*16*64 = 262144
  int g = id & 63, s2 = id >> 6;
  int b = s2 >> 4, r = s2 & 15;
  int oy = r >> 2, ox = r & 3;
  int ys = oy == 0 ? 0 : (oy == 1 ? 1 : (oy == 2 ? 3 : 4));
  int yn = (oy == 1 || oy == 3) ? 2 : 1;
  int xs = ox == 0 ? 0 : (ox == 1 ? 1 : (ox == 2 ? 3 : 4));
  int xn = (ox == 1 || ox == 3) ? 2 : 1;
  float bg = bias[g];
  const size_t CS = (size_t)36 * 256 * 64;
  float vmax = -3.4e38f;
  for (int yy = ys; yy < ys + yn; yy++)
    for (int xx = xs; xx < xs + xn; xx++) {
      size_t e = (size_t)((yy * 6 + xx) * 256 + b) * 64 + g;
      float v = P[e] + P[CS + e] + P[2 * CS + e] + bg;
      vmax = fmaxf(vmax, elu_f(v));
    }
  h2p[(size_t)s2 * 64 + g] = vmax;
}

// ---- D5: redpool3 (9 partials) + pool 4x4->2x2 + FC head, 1 block/image ---
__global__ __launch_bounds__(256) void fc_fused_kernel(
    const float* __restrict__ P, const float* __restrict__ b3,
    const float* __restrict__ fc1w, const float* __restrict__ fc1b,
    const float* __restrict__ fc2w, const float* __restrict__ fc2b,
    float* __restrict__ out) {
  __shared__ float h3[16][64];
  __shared__ float Al[256];
  __shared__ float part[256];
  __shared__ float h4[128];
  __shared__ float lg[10];
  int b = blockIdx.x, t = threadIdx.x;
  const size_t CS = (size_t)16 * 256 * 64;
  // sum partials + bias + ELU -> h3[16][64]
#pragma unroll
  for (int i = 0; i < 4; i++) {
    int idx = i * 256 + t;            // 0..1023
    int cell = idx >> 6, g = idx & 63;
    float v = b3[g];
    size_t e = (size_t)(cell * 256 + b) * 64 + g;
#pragma unroll
    for (int q = 0; q < 9; q++) v += P[q * CS + e];
    h3[cell][g] = elu_f(v);
  }
  __syncthreads();
  // pool 4x4 -> 2x2 into Al[r*64+g], r = oy*2+ox
  {
    int r = t >> 6, g = t & 63;
    int oy = r >> 1, ox = r & 1;
    float m = -3.4e38f;
#pragma unroll
    for (int i = 0; i < 2; i++)
#pragma unroll
      for (int j = 0; j < 2; j++)
        m = fmaxf(m, h3[(oy * 2 + i) * 4 + (ox * 2 + j)][g]);
    Al[t] = m;
  }
  __syncthreads();
  // FC1 split-K: t = half*128 + o
  {
    int o = t & 127, half = t >> 7;
    float acc = 0.f;
    const float* wcol = fc1w + o;
#pragma unroll 8
    for (int k = half * 128; k < half * 128 + 128; k++)
      acc += Al[k] * wcol[k * 128];
    part[t] = acc;
  }
  __syncthreads();
  if (t < 128)
    h4[t] = elu_f(part[t] + part[t + 128] + fc1b[t]);
  __syncthreads();
  if (t < 10) {
    float l = fc2b[t];
#pragma unroll 8
    for (int k = 0; k < 128; k++) l += h4[k] * fc2w[k * 10 + t];
    lg[t] = l;
  }
  __syncthreads();
  if (t < 10) {
    float m = lg[0];
#pragma unroll
    for (int j = 1; j < 10; j++) m = fmaxf(m, lg[j]);
    float ssum = 0.f;
#pragma unroll
    for (int j = 0; j < 10; j++) ssum += expf(lg[j] - m);
    out[b * 10 + t] = lg[t] - m - logf(ssum);
  }
}

// ---------------------------------------------------------------------------
extern "C" void kernel_launch(void* const* d_in, const int* in_sizes, int n_in,
                              void* d_out, int out_size, void* d_ws, size_t ws_size,
                              hipStream_t stream) {
  const float* x     = (const float*)d_in[0];
  const float* W1    = (const float*)d_in[3];
  const float* root1 = (const float*)d_in[4];
  const float* b1    = (const float*)d_in[5];
  const float* W2    = (const float*)d_in[6];
  const float* root2 = (const float*)d_in[7];
  const float* b2    = (const float*)d_in[8];
  const float* W3    = (const float*)d_in[9];
  const float* root3 = (const float*)d_in[10];
  const float* b3    = (const float*)d_in[11];
  const float* fc1w  = (const float*)d_in[12];
  const float* fc1b  = (const float*)d_in[13];
  const float* fc2w  = (const float*)d_in[14];
  const float* fc2b  = (const float*)d_in[15];
  float* out = (float*)d_out;

  float* ws = (float*)d_ws;
  size_t o = 0;
  float* w_h1p = ws + o; o += (size_t)9216 * 32;          // 294912
  float* w_M2  = ws + o; o += (size_t)36 * 9 * 32 * 64;   // 663552
  float* w_M3  = ws + o; o += (size_t)16 * 9 * 64 * 64;   // 589824
  float* w_P   = ws + o; o += (size_t)9 * 16 * 256 * 64;  // 2359296 (>= L2's 3*36*256*64)
  float* w_h2p = ws + o; o += (size_t)4096 * 64;

  // D1: s1p1 (1152 blocks) || prepM (4896 blocks)
  prep_kernel<<<6048, 256, 0, stream>>>(x, W1, root1, b1, W2, root2, W3, root3,
                                        w_h1p, w_M2, w_M3);
  // D2: L2 class-GEMM, 36c x 4 rowtiles x S=3 = 432 blocks
  gemm_cls_tk<36, 5, 36, 3, 6><<<dim3(4, 36, 3), 256, 0, stream>>>(w_h1p, w_M2, w_P);
  // D3: reduce+ELU+pool 6x6->4x4
  redpool2_kernel<<<1024, 256, 0, stream>>>(w_P, b2, w_h2p);
  // D4: L3 class-GEMM, 16c x 4 rowtiles x S=9 = 576 blocks
  gemm_cls_tk<16, 6, 16, 1, 4><<<dim3(4, 16, 9), 256, 0, stream>>>(w_h2p, w_M3, w_P);
  // D5: redpool3 + FC head fused
  fc_fused_kernel<<<256, 256, 0, stream>>>(w_P, b3, fc1w, fc1b, fc2w, fc2b, out);
}